// Round 1
// baseline (13911.061 us; speedup 1.0000x reference)
//
#include <hip/hip_runtime.h>

typedef unsigned int u32;
typedef unsigned short u16;
using u32x4 = __attribute__((ext_vector_type(4))) u32;
using f16x8 = __attribute__((ext_vector_type(8))) _Float16;
using f32x4 = __attribute__((ext_vector_type(4))) float;

#define LT 512
#define BNB 64
#define ED 512
#define HD 1024
#define OUT_HALF_BYTES ((size_t)LT * BNB * HD * 4)  // 134217728 bytes per output tensor

// workspace layout (bytes)
#define WXP_OFF  ((size_t)0)                         // 4 MB  f16 fragment-packed Wx
#define WHP_OFF  ((size_t)(4u << 20))                // 8 MB  f16 fragment-packed Wh
#define BIAS_OFF ((size_t)(12u << 20))               // 16 KB packed bias (f32)
#define HSTG_OFF ((size_t)((12u << 20) + (16u << 10)))          // 256 KB h ping-pong (f16)
#define FLAG_OFF ((size_t)((12u << 20) + (16u << 10) + (256u << 10)))  // 1 KB barrier flags

__device__ __forceinline__ u16 f2h(float f) {
  _Float16 h = (_Float16)f;
  return __builtin_bit_cast(u16, h);
}
__device__ __forceinline__ float h2f(u16 s) {
  return (float)__builtin_bit_cast(_Float16, s);
}
__device__ __forceinline__ u32 pk2(float a, float b) {
  return (u32)f2h(a) | ((u32)f2h(b) << 16);
}
__device__ __forceinline__ void glds16(const void* g, void* l) {
  using GP = const __attribute__((address_space(1))) u32*;
  using SP = __attribute__((address_space(3))) u32*;
  __builtin_amdgcn_global_load_lds((GP)g, (SP)l, 16, 0, 0);
}
__device__ __forceinline__ f32x4 mfma_f16(f16x8 a, f16x8 b, f32x4 c) {
  return __builtin_amdgcn_mfma_f32_16x16x32_f16(a, b, c, 0, 0, 0);
}
__device__ __forceinline__ float sigm(float x) { return 1.0f / (1.0f + __expf(-x)); }
__device__ __forceinline__ float tanh_(float x) { return 2.0f / (1.0f + __expf(-2.0f * x)) - 1.0f; }

// ---------------- weight packing ----------------
// fragment convention for mfma_f32_16x16x32: lane l holds
//   A[row=l&15][k=8*(l>>4)+i]   B[k=8*(l>>4)+i][col=l&15]   (i=0..7, 16B per lane)
// gate-interleaved column index: n' = cg*64 + g*16 + j  (cg=0..63, g=f/i/g/o, j=0..15)

__global__ void pack_wx(const float* __restrict__ Wf, const float* __restrict__ Wi,
                        const float* __restrict__ Wg, const float* __restrict__ Wo,
                        u32x4* __restrict__ dst) {
  const int id = blockIdx.x * 256 + threadIdx.x;  // 262144 = 4096 frag-rows * 64 lanes
  const int lane = id & 63;
  const int row = id >> 6;           // ((ntile*16 + kt)*8 + fn)
  const int ntile = row >> 7;
  const int rem = row & 127;
  const int kt = rem >> 3;
  const int fn = rem & 7;
  const int np = (ntile << 7) + (fn << 4) + (lane & 15);
  const int g = (np >> 4) & 3;
  const int jfull = ((np >> 6) << 4) + (np & 15);
  const int k0 = (kt << 5) + ((lane >> 4) << 3);
  const float* W = (g == 0) ? Wf : (g == 1) ? Wi : (g == 2) ? Wg : Wo;
  const float* s = W + (size_t)k0 * HD + jfull;
  u16 h[8];
#pragma unroll
  for (int i = 0; i < 8; ++i) h[i] = f2h(s[(size_t)i * HD]);
  u32x4 v;
  v[0] = (u32)h[0] | ((u32)h[1] << 16);
  v[1] = (u32)h[2] | ((u32)h[3] << 16);
  v[2] = (u32)h[4] | ((u32)h[5] << 16);
  v[3] = (u32)h[6] | ((u32)h[7] << 16);
  dst[id] = v;
}

__global__ void pack_wh(const float* __restrict__ Wf, const float* __restrict__ Wi,
                        const float* __restrict__ Wg, const float* __restrict__ Wo,
                        u32x4* __restrict__ dst) {
  const int id = blockIdx.x * 256 + threadIdx.x;  // 524288 = 8192 frag-rows * 64 lanes
  const int lane = id & 63;
  const int row = id >> 6;           // ((cg*4 + w)*4 + g)*8 + kk
  const int cg = row >> 7;
  const int rem = row & 127;
  const int w = rem >> 5;
  const int g = (rem >> 3) & 3;
  const int kk = rem & 7;
  const int k = ED + (w << 8) + (kk << 5) + ((lane >> 4) << 3);  // h-part rows of W
  const int j = (cg << 4) + (lane & 15);
  const float* W = (g == 0) ? Wf : (g == 1) ? Wi : (g == 2) ? Wg : Wo;
  const float* s = W + (size_t)k * HD + j;
  u16 h[8];
#pragma unroll
  for (int i = 0; i < 8; ++i) h[i] = f2h(s[(size_t)i * HD]);
  u32x4 v;
  v[0] = (u32)h[0] | ((u32)h[1] << 16);
  v[1] = (u32)h[2] | ((u32)h[3] << 16);
  v[2] = (u32)h[4] | ((u32)h[5] << 16);
  v[3] = (u32)h[6] | ((u32)h[7] << 16);
  dst[id] = v;
}

__global__ void pack_bias_flags(const float* __restrict__ bf, const float* __restrict__ bi,
                                const float* __restrict__ bg, const float* __restrict__ bo,
                                float* __restrict__ dst, int* __restrict__ flags) {
  const int id = blockIdx.x * 256 + threadIdx.x;  // 4096
  const int g = (id >> 4) & 3;
  const int jfull = ((id >> 6) << 4) + (id & 15);
  const float* B = (g == 0) ? bf : (g == 1) ? bi : (g == 2) ? bg : bo;
  dst[id] = B[jfull];
  if (id < 256) flags[id] = 0;  // reset grid barrier every call (graph-replay safe)
}

// ---------------- zx = X @ Wx + b  (written f16 into d_out's own bytes) ----------------
// zx element (m=t*64+b, n'=cg*64+g*16+j) lives at:
//   (g<2 ? c_half : h_half) + m*4096 + cg*64 + (g&1)*32 + j*2
// i.e. exactly the bytes that step t of the recurrence later overwrites with c/h.

__global__ __launch_bounds__(256) void zx_gemm(const float* __restrict__ x,
                                               const u32x4* __restrict__ wxp,
                                               const float* __restrict__ biasp,
                                               char* __restrict__ outb) {
  __shared__ u32x4 Ab[512];  // 8 KB  [fm 0..7][lane][16B]
  __shared__ u32x4 Bb[512];  // 8 KB  [fn 0..7][lane][16B]
  const int bid = blockIdx.x;
  const int ntile = bid & 31;
  const int mtile = bid >> 5;
  const int tid = threadIdx.x;
  const int lane = tid & 63;
  const int wid = tid >> 6;
  const int wm = wid & 1;
  const int wn = wid >> 1;
  const int m0 = mtile << 7;

  const f32x4 fz = {0.f, 0.f, 0.f, 0.f};
  f32x4 acc[4][4];
#pragma unroll
  for (int i = 0; i < 4; ++i)
#pragma unroll
    for (int j = 0; j < 4; ++j) acc[i][j] = fz;

  for (int kt = 0; kt < 16; ++kt) {
    // stage A: f32 -> f16 via regs, fragment-linear LDS
#pragma unroll
    for (int r = 0; r < 2; ++r) {
      const int c = tid + (r << 8);
      const int fl = c & 63;
      const int fmg = c >> 6;
      const int row = m0 + (fmg << 4) + (fl & 15);
      const int kc = (kt << 5) + ((fl >> 4) << 3);
      const float* s = x + (size_t)row * ED + kc;
      const float4 p0 = *(const float4*)s;
      const float4 p1 = *(const float4*)(s + 4);
      u32x4 v;
      v[0] = pk2(p0.x, p0.y);
      v[1] = pk2(p0.z, p0.w);
      v[2] = pk2(p1.x, p1.y);
      v[3] = pk2(p1.z, p1.w);
      Ab[c] = v;
    }
    // stage B: already packed, async global->LDS (dest = wave base + lane*16)
    {
      const u32x4* bsrc = wxp + (((size_t)(ntile << 4) + kt) << 9);
#pragma unroll
      for (int r = 0; r < 2; ++r) {
        const int cb = (wid << 6) + (r << 8);
        glds16((const void*)(bsrc + cb + lane), (void*)&Bb[cb]);
      }
    }
    __syncthreads();
    f16x8 afr[4], bfr[4];
#pragma unroll
    for (int f = 0; f < 4; ++f) afr[f] = __builtin_bit_cast(f16x8, Ab[((wm * 4 + f) << 6) + lane]);
#pragma unroll
    for (int f = 0; f < 4; ++f) bfr[f] = __builtin_bit_cast(f16x8, Bb[((wn * 4 + f) << 6) + lane]);
#pragma unroll
    for (int fm = 0; fm < 4; ++fm)
#pragma unroll
      for (int fn = 0; fn < 4; ++fn) acc[fm][fn] = mfma_f16(afr[fm], bfr[fn], acc[fm][fn]);
    __syncthreads();
  }

  char* const cb_ = outb;
  char* const hb_ = outb + OUT_HALF_BYTES;
  const int r0 = (lane >> 4) << 2;
#pragma unroll
  for (int fn = 0; fn < 4; ++fn) {
    const int np = (ntile << 7) + (wn << 6) + (fn << 4) + (lane & 15);
    const float bv = biasp[np];
    const int gg = (np >> 4) & 3;
    const int cg = np >> 6;
    const int jj = np & 15;
    char* const outHalf = (gg < 2) ? cb_ : hb_;
    const size_t coloff = (size_t)(cg << 6) + ((gg & 1) << 5) + (jj << 1);
#pragma unroll
    for (int fm = 0; fm < 4; ++fm) {
#pragma unroll
      for (int r = 0; r < 4; ++r) {
        const int m = m0 + (wm << 6) + (fm << 4) + r0 + r;
        *(u16*)(outHalf + (size_t)m * 4096 + coloff) = f2h(acc[fm][fn][r] + bv);
      }
    }
  }
}

// ---------------- persistent recurrence ----------------
// distributed grid barrier: 256 blocks, each thread polls one block's flag.
__device__ __forceinline__ void grid_bar(int* flags, int gen) {
  __syncthreads();
  if (threadIdx.x == 0)
    __hip_atomic_store(&flags[blockIdx.x], gen, __ATOMIC_RELEASE, __HIP_MEMORY_SCOPE_AGENT);
  while (__hip_atomic_load(&flags[threadIdx.x], __ATOMIC_ACQUIRE, __HIP_MEMORY_SCOPE_AGENT) < gen)
    __builtin_amdgcn_s_sleep(1);
  __syncthreads();
}

__global__ __launch_bounds__(256, 1) void lstm_rec(const float* __restrict__ c0,
                                                   const float* __restrict__ h0,
                                                   const u32x4* __restrict__ whp, char* outb,
                                                   u16* hstage, int* flags) {
  __shared__ u32x4 Ab[2048];          // 32 KB h fragments [kk 0..31][lane][16B]
  __shared__ float zb[4][4][16][17];  // 17 KB partial z [kchunk][gate][row][col+pad]
  const int bid = blockIdx.x;
  const int mslab = bid & 3;   // batch slab (16 rows); bid%8 keeps slab uniform per XCD
  const int cgp = bid >> 2;    // column group (16 h-cols x 4 gates)
  const int tid = threadIdx.x;
  const int lane = tid & 63;
  const int wid = tid >> 6;    // K-chunk of 256
  const int b_loc = tid >> 4;
  const int j_loc = tid & 15;
  const int b = (mslab << 4) + b_loc;
  const int jf = (cgp << 4) + j_loc;

  // Wh slice -> VGPRs (4 gates x 8 kk x 16B/lane = 128 VGPR), loaded once
  f16x8 wreg[4][8];
  {
    const u32x4* wb = whp + (((size_t)(cgp * 4 + wid)) << 11);
#pragma unroll
    for (int g = 0; g < 4; ++g)
#pragma unroll
      for (int kk = 0; kk < 8; ++kk)
        wreg[g][kk] = __builtin_bit_cast(f16x8, wb[((g << 3) + kk) * 64 + lane]);
  }
  float creg = c0[(b << 10) + jf];
  hstage[(b << 10) + jf] = f2h(h0[(b << 10) + jf]);

  char* const cb_ = outb;
  char* const hb_ = outb + OUT_HALF_BYTES;

  grid_bar(flags, 1);

  const f32x4 fz = {0.f, 0.f, 0.f, 0.f};
#pragma unroll 1
  for (int t = 0; t < LT; ++t) {
    const size_t rowoff = ((size_t)(t * 64 + b)) << 12;
    const char* crow = cb_ + rowoff + (cgp << 6);
    const char* hrow = hb_ + rowoff + (cgp << 6);
    // early zx loads (these bytes are overwritten by this thread's own c/h stores below;
    // the stores are data-dependent on the loads, so ordering is guaranteed)
    const u16 xf16 = *(const u16*)(crow + (j_loc << 1));
    const u16 xi16 = *(const u16*)(crow + 32 + (j_loc << 1));
    const u16 xg16 = *(const u16*)(hrow + (j_loc << 1));
    const u16 xo16 = *(const u16*)(hrow + 32 + (j_loc << 1));

    // stage h slab (16 rows x 1024) into fragment-linear LDS
    const u16* hsrc = hstage + ((size_t)(t & 1) << 16);
#pragma unroll
    for (int it = 0; it < 8; ++it) {
      const int kk = (it << 2) + wid;
      const u16* src =
          hsrc + (((mslab << 4) + (lane & 15)) << 10) + (kk << 5) + ((lane >> 4) << 3);
      glds16((const void*)src, (void*)&Ab[kk << 6]);
    }
    __syncthreads();

    f32x4 a0 = fz, a1 = fz, a2 = fz, a3 = fz;
#pragma unroll
    for (int kk = 0; kk < 8; ++kk) {
      const f16x8 av = __builtin_bit_cast(f16x8, Ab[((wid << 3) + kk) * 64 + lane]);
      a0 = mfma_f16(av, wreg[0][kk], a0);
      a1 = mfma_f16(av, wreg[1][kk], a1);
      a2 = mfma_f16(av, wreg[2][kk], a2);
      a3 = mfma_f16(av, wreg[3][kk], a3);
    }
    {
      const int rr = (lane >> 4) << 2;
      const int cc = lane & 15;
#pragma unroll
      for (int r = 0; r < 4; ++r) {
        zb[wid][0][rr + r][cc] = a0[r];
        zb[wid][1][rr + r][cc] = a1[r];
        zb[wid][2][rr + r][cc] = a2[r];
        zb[wid][3][rr + r][cc] = a3[r];
      }
    }
    __syncthreads();

    float zf = h2f(xf16), zi = h2f(xi16), zg = h2f(xg16), zo = h2f(xo16);
#pragma unroll
    for (int w = 0; w < 4; ++w) {
      zf += zb[w][0][b_loc][j_loc];
      zi += zb[w][1][b_loc][j_loc];
      zg += zb[w][2][b_loc][j_loc];
      zo += zb[w][3][b_loc][j_loc];
    }
    const float fgate = sigm(zf);
    const float igate = sigm(zi);
    const float ggate = tanh_(zg);
    const float ogate = sigm(zo);
    creg = creg * fgate + igate * ggate;
    const float hv = ogate * tanh_(creg);
    *(float*)(cb_ + rowoff + ((size_t)jf << 2)) = creg;
    *(float*)(hb_ + rowoff + ((size_t)jf << 2)) = hv;
    hstage[(((size_t)(t + 1) & 1) << 16) + (b << 10) + jf] = f2h(hv);

    grid_bar(flags, t + 2);
  }
}

extern "C" void kernel_launch(void* const* d_in, const int* in_sizes, int n_in, void* d_out,
                              int out_size, void* d_ws, size_t ws_size, hipStream_t stream) {
  const float* x = (const float*)d_in[0];
  const float* c0 = (const float*)d_in[1];
  const float* h0 = (const float*)d_in[2];
  const float* Wf = (const float*)d_in[3];
  const float* bf = (const float*)d_in[4];
  const float* Wi = (const float*)d_in[5];
  const float* bi = (const float*)d_in[6];
  const float* Wg = (const float*)d_in[7];
  const float* bg = (const float*)d_in[8];
  const float* Wo = (const float*)d_in[9];
  const float* bo = (const float*)d_in[10];

  char* ws = (char*)d_ws;
  u32x4* wxp = (u32x4*)(ws + WXP_OFF);
  u32x4* whp = (u32x4*)(ws + WHP_OFF);
  float* bp = (float*)(ws + BIAS_OFF);
  u16* hstage = (u16*)(ws + HSTG_OFF);
  int* flags = (int*)(ws + FLAG_OFF);

  pack_wx<<<1024, 256, 0, stream>>>(Wf, Wi, Wg, Wo, wxp);
  pack_wh<<<2048, 256, 0, stream>>>(Wf, Wi, Wg, Wo, whp);
  pack_bias_flags<<<16, 256, 0, stream>>>(bf, bi, bg, bo, bp, flags);
  zx_gemm<<<8192, 256, 0, stream>>>(x, wxp, bp, (char*)d_out);
  lstm_rec<<<256, 256, 0, stream>>>(c0, h0, whp, (char*)d_out, hstage, flags);
}

// Round 2
// 2289.898 us; speedup vs baseline: 6.0750x; 6.0750x over previous
//
#include <hip/hip_runtime.h>

typedef unsigned int u32;
typedef unsigned short u16;
using u32x4 = __attribute__((ext_vector_type(4))) u32;
using f16x8 = __attribute__((ext_vector_type(8))) _Float16;
using f32x4 = __attribute__((ext_vector_type(4))) float;

#define LT 512
#define BNB 64
#define ED 512
#define HD 1024
#define OUT_HALF_BYTES ((size_t)LT * BNB * HD * 4)  // 134217728 bytes per output tensor

// workspace layout (bytes)
#define WXP_OFF  ((size_t)0)                         // 4 MB  f16 fragment-packed Wx
#define WHP_OFF  ((size_t)(4u << 20))                // 8 MB  f16 fragment-packed Wh
#define BIAS_OFF ((size_t)(12u << 20))               // 16 KB packed bias (f32)
#define HSTG_OFF ((size_t)((12u << 20) + (16u << 10)))          // 256 KB h ping-pong (f16)
#define FLAG_OFF ((size_t)((12u << 20) + (16u << 10) + (256u << 10)))  // 16 KB barrier flags (64B-padded)

__device__ __forceinline__ u16 f2h(float f) {
  _Float16 h = (_Float16)f;
  return __builtin_bit_cast(u16, h);
}
__device__ __forceinline__ float h2f(u16 s) {
  return (float)__builtin_bit_cast(_Float16, s);
}
__device__ __forceinline__ u32 pk2(float a, float b) {
  return (u32)f2h(a) | ((u32)f2h(b) << 16);
}
__device__ __forceinline__ void glds16(const void* g, void* l) {
  using GP = const __attribute__((address_space(1))) u32*;
  using SP = __attribute__((address_space(3))) u32*;
  __builtin_amdgcn_global_load_lds((GP)g, (SP)l, 16, 0, 0);
}
__device__ __forceinline__ f32x4 mfma_f16(f16x8 a, f16x8 b, f32x4 c) {
  return __builtin_amdgcn_mfma_f32_16x16x32_f16(a, b, c, 0, 0, 0);
}
__device__ __forceinline__ float sigm(float x) { return 1.0f / (1.0f + __expf(-x)); }
__device__ __forceinline__ float tanh_(float x) { return 2.0f / (1.0f + __expf(-2.0f * x)) - 1.0f; }

// ---- coherent (LLC-level, cross-XCD) memory ops: bypass L1+L2 with sc0 sc1 ----
__device__ __forceinline__ u32x4 ldg16_cc(const void* p) {
  u32x4 r;
  asm volatile("global_load_dwordx4 %0, %1, off sc0 sc1" : "=v"(r) : "v"(p) : "memory");
  return r;
}
__device__ __forceinline__ u32 ldg_u32_cc(const void* p) {
  u32 r;
  asm volatile("global_load_dword %0, %1, off sc0 sc1\n\ts_waitcnt vmcnt(0)"
               : "=v"(r) : "v"(p) : "memory");
  return r;
}
__device__ __forceinline__ void stg_u16_cc(void* p, u32 v) {
  asm volatile("global_store_short %0, %1, off sc0 sc1" ::"v"(p), "v"(v) : "memory");
}
__device__ __forceinline__ void stg_u32_cc(void* p, u32 v) {
  asm volatile("global_store_dword %0, %1, off sc0 sc1" ::"v"(p), "v"(v) : "memory");
}
__device__ __forceinline__ u32 ldg_u16_plain(const void* p) {
  u32 r;
  asm volatile("global_load_ushort %0, %1, off" : "=v"(r) : "v"(p) : "memory");
  return r;
}
__device__ __forceinline__ void waitv0() { asm volatile("s_waitcnt vmcnt(0)" ::: "memory"); }

// ---------------- weight packing ----------------
// fragment convention for mfma_f32_16x16x32: lane l holds
//   A[row=l&15][k=8*(l>>4)+i]   B[k=8*(l>>4)+i][col=l&15]   (i=0..7, 16B per lane)
// gate-interleaved column index: n' = cg*64 + g*16 + j  (cg=0..63, g=f/i/g/o, j=0..15)

__global__ void pack_wx(const float* __restrict__ Wf, const float* __restrict__ Wi,
                        const float* __restrict__ Wg, const float* __restrict__ Wo,
                        u32x4* __restrict__ dst) {
  const int id = blockIdx.x * 256 + threadIdx.x;  // 262144 = 4096 frag-rows * 64 lanes
  const int lane = id & 63;
  const int row = id >> 6;           // ((ntile*16 + kt)*8 + fn)
  const int ntile = row >> 7;
  const int rem = row & 127;
  const int kt = rem >> 3;
  const int fn = rem & 7;
  const int np = (ntile << 7) + (fn << 4) + (lane & 15);
  const int g = (np >> 4) & 3;
  const int jfull = ((np >> 6) << 4) + (np & 15);
  const int k0 = (kt << 5) + ((lane >> 4) << 3);
  const float* W = (g == 0) ? Wf : (g == 1) ? Wi : (g == 2) ? Wg : Wo;
  const float* s = W + (size_t)k0 * HD + jfull;
  u16 h[8];
#pragma unroll
  for (int i = 0; i < 8; ++i) h[i] = f2h(s[(size_t)i * HD]);
  u32x4 v;
  v[0] = (u32)h[0] | ((u32)h[1] << 16);
  v[1] = (u32)h[2] | ((u32)h[3] << 16);
  v[2] = (u32)h[4] | ((u32)h[5] << 16);
  v[3] = (u32)h[6] | ((u32)h[7] << 16);
  dst[id] = v;
}

__global__ void pack_wh(const float* __restrict__ Wf, const float* __restrict__ Wi,
                        const float* __restrict__ Wg, const float* __restrict__ Wo,
                        u32x4* __restrict__ dst) {
  const int id = blockIdx.x * 256 + threadIdx.x;  // 524288 = 8192 frag-rows * 64 lanes
  const int lane = id & 63;
  const int row = id >> 6;           // ((cg*4 + w)*4 + g)*8 + kk
  const int cg = row >> 7;
  const int rem = row & 127;
  const int w = rem >> 5;
  const int g = (rem >> 3) & 3;
  const int kk = rem & 7;
  const int k = ED + (w << 8) + (kk << 5) + ((lane >> 4) << 3);  // h-part rows of W
  const int j = (cg << 4) + (lane & 15);
  const float* W = (g == 0) ? Wf : (g == 1) ? Wi : (g == 2) ? Wg : Wo;
  const float* s = W + (size_t)k * HD + j;
  u16 h[8];
#pragma unroll
  for (int i = 0; i < 8; ++i) h[i] = f2h(s[(size_t)i * HD]);
  u32x4 v;
  v[0] = (u32)h[0] | ((u32)h[1] << 16);
  v[1] = (u32)h[2] | ((u32)h[3] << 16);
  v[2] = (u32)h[4] | ((u32)h[5] << 16);
  v[3] = (u32)h[6] | ((u32)h[7] << 16);
  dst[id] = v;
}

__global__ void pack_bias_flags(const float* __restrict__ bf, const float* __restrict__ bi,
                                const float* __restrict__ bg, const float* __restrict__ bo,
                                float* __restrict__ dst, int* __restrict__ flags) {
  const int id = blockIdx.x * 256 + threadIdx.x;  // 4096
  const int g = (id >> 4) & 3;
  const int jfull = ((id >> 6) << 4) + (id & 15);
  const float* B = (g == 0) ? bf : (g == 1) ? bi : (g == 2) ? bg : bo;
  dst[id] = B[jfull];
  flags[id] = 0;  // reset 16KB padded barrier flags every call (graph-replay safe)
}

// ---------------- zx = X @ Wx + b  (written f16 into d_out's own bytes) ----------------
// zx element (m=t*64+b, n'=cg*64+g*16+j) lives at:
//   (g<2 ? c_half : h_half) + m*4096 + cg*64 + (g&1)*32 + j*2
// i.e. exactly the bytes that step t of the recurrence later overwrites with c/h.

__global__ __launch_bounds__(256) void zx_gemm(const float* __restrict__ x,
                                               const u32x4* __restrict__ wxp,
                                               const float* __restrict__ biasp,
                                               char* __restrict__ outb) {
  __shared__ u32x4 Ab[512];  // 8 KB  [fm 0..7][lane][16B]
  __shared__ u32x4 Bb[512];  // 8 KB  [fn 0..7][lane][16B]
  const int bid = blockIdx.x;
  const int ntile = bid & 31;
  const int mtile = bid >> 5;
  const int tid = threadIdx.x;
  const int lane = tid & 63;
  const int wid = tid >> 6;
  const int wm = wid & 1;
  const int wn = wid >> 1;
  const int m0 = mtile << 7;

  const f32x4 fz = {0.f, 0.f, 0.f, 0.f};
  f32x4 acc[4][4];
#pragma unroll
  for (int i = 0; i < 4; ++i)
#pragma unroll
    for (int j = 0; j < 4; ++j) acc[i][j] = fz;

  for (int kt = 0; kt < 16; ++kt) {
    // stage A: f32 -> f16 via regs, fragment-linear LDS
#pragma unroll
    for (int r = 0; r < 2; ++r) {
      const int c = tid + (r << 8);
      const int fl = c & 63;
      const int fmg = c >> 6;
      const int row = m0 + (fmg << 4) + (fl & 15);
      const int kc = (kt << 5) + ((fl >> 4) << 3);
      const float* s = x + (size_t)row * ED + kc;
      const float4 p0 = *(const float4*)s;
      const float4 p1 = *(const float4*)(s + 4);
      u32x4 v;
      v[0] = pk2(p0.x, p0.y);
      v[1] = pk2(p0.z, p0.w);
      v[2] = pk2(p1.x, p1.y);
      v[3] = pk2(p1.z, p1.w);
      Ab[c] = v;
    }
    // stage B: already packed, async global->LDS (dest = wave base + lane*16)
    {
      const u32x4* bsrc = wxp + (((size_t)(ntile << 4) + kt) << 9);
#pragma unroll
      for (int r = 0; r < 2; ++r) {
        const int cb = (wid << 6) + (r << 8);
        glds16((const void*)(bsrc + cb + lane), (void*)&Bb[cb]);
      }
    }
    __syncthreads();
    f16x8 afr[4], bfr[4];
#pragma unroll
    for (int f = 0; f < 4; ++f) afr[f] = __builtin_bit_cast(f16x8, Ab[((wm * 4 + f) << 6) + lane]);
#pragma unroll
    for (int f = 0; f < 4; ++f) bfr[f] = __builtin_bit_cast(f16x8, Bb[((wn * 4 + f) << 6) + lane]);
#pragma unroll
    for (int fm = 0; fm < 4; ++fm)
#pragma unroll
      for (int fn = 0; fn < 4; ++fn) acc[fm][fn] = mfma_f16(afr[fm], bfr[fn], acc[fm][fn]);
    __syncthreads();
  }

  char* const cb_ = outb;
  char* const hb_ = outb + OUT_HALF_BYTES;
  const int r0 = (lane >> 4) << 2;
#pragma unroll
  for (int fn = 0; fn < 4; ++fn) {
    const int np = (ntile << 7) + (wn << 6) + (fn << 4) + (lane & 15);
    const float bv = biasp[np];
    const int gg = (np >> 4) & 3;
    const int cg = np >> 6;
    const int jj = np & 15;
    char* const outHalf = (gg < 2) ? cb_ : hb_;
    const size_t coloff = (size_t)(cg << 6) + ((gg & 1) << 5) + (jj << 1);
#pragma unroll
    for (int fm = 0; fm < 4; ++fm) {
#pragma unroll
      for (int r = 0; r < 4; ++r) {
        const int m = m0 + (wm << 6) + (fm << 4) + r0 + r;
        *(u16*)(outHalf + (size_t)m * 4096 + coloff) = f2h(acc[fm][fn][r] + bv);
      }
    }
  }
}

// ---------------- persistent recurrence ----------------
// 4 independent barrier groups (one per 16-row batch slab): z[b,:] depends only
// on h[b,:], so only the 64 blocks sharing a slab must synchronize.
// Cross-XCD exchange (hstage + flags) uses sc0|sc1 ops at the LLC coherence
// point; NO release/acquire fences -> no buffer_wbl2 / buffer_inv per step.

__global__ __launch_bounds__(256, 1) void lstm_rec(const float* __restrict__ c0,
                                                   const float* __restrict__ h0,
                                                   const u32x4* __restrict__ whp, char* outb,
                                                   u16* hstage, int* flags) {
  __shared__ u32x4 Ab[2048];          // 32 KB h fragments [kk 0..31][lane][16B]
  __shared__ float zb[4][4][16][17];  // 17 KB partial z [kchunk][gate][row][col+pad]
  const int bid = blockIdx.x;
  const int mslab = bid & 3;   // batch slab (16 rows)
  const int cgp = bid >> 2;    // column group (16 h-cols x 4 gates)
  const int tid = threadIdx.x;
  const int lane = tid & 63;
  const int wid = tid >> 6;    // K-chunk of 256
  const int b_loc = tid >> 4;
  const int j_loc = tid & 15;
  const int b = (mslab << 4) + b_loc;
  const int jf = (cgp << 4) + j_loc;

  // Wh slice -> VGPRs (4 gates x 8 kk x 16B/lane = 128 VGPR), loaded once
  f16x8 wreg[4][8];
  {
    const u32x4* wb = whp + (((size_t)(cgp * 4 + wid)) << 11);
#pragma unroll
    for (int g = 0; g < 4; ++g)
#pragma unroll
      for (int kk = 0; kk < 8; ++kk)
        wreg[g][kk] = __builtin_bit_cast(f16x8, wb[((g << 3) + kk) * 64 + lane]);
  }
  float creg = c0[(b << 10) + jf];
  stg_u16_cc(hstage + (b << 10) + jf, (u32)f2h(h0[(b << 10) + jf]));

  char* const cb_ = outb;
  char* const hb_ = outb + OUT_HALF_BYTES;
  int* const myflag = flags + (((cgp << 2) + mslab) << 4);            // 64B padded
  int* const pollflag = flags + ((((tid & 63) << 2) + mslab) << 4);   // member (tid) of my group

  // ---- initial barrier (gen 1) ----
  waitv0();         // own wave's hstage store retired at LLC
  __syncthreads();  // all waves retired
  if (tid == 0) stg_u32_cc(myflag, 1u);
  // prefetch zx for t=0 (plain cached loads; written by zx_gemm, prior kernel)
  u32 xf16, xi16, xg16, xo16;
  {
    const size_t rowoff = ((size_t)b) << 12;
    const char* crow = cb_ + rowoff + (cgp << 6);
    const char* hrow = hb_ + rowoff + (cgp << 6);
    xf16 = ldg_u16_plain(crow + (j_loc << 1));
    xi16 = ldg_u16_plain(crow + 32 + (j_loc << 1));
    xg16 = ldg_u16_plain(hrow + (j_loc << 1));
    xo16 = ldg_u16_plain(hrow + 32 + (j_loc << 1));
  }
  if (tid < 64) {
    while ((int)ldg_u32_cc(pollflag) < 1) {}
  }
  __syncthreads();

  const f32x4 fz = {0.f, 0.f, 0.f, 0.f};
#pragma unroll 1
  for (int t = 0; t < LT; ++t) {
    // issue coherent hstage loads (producers may be on other XCDs)
    const u16* hsrc = hstage + ((size_t)(t & 1) << 16);
    u32x4 hreg[8];
#pragma unroll
    for (int it = 0; it < 8; ++it) {
      const int kk = (it << 2) + wid;
      const u16* src =
          hsrc + (((mslab << 4) + (lane & 15)) << 10) + (kk << 5) + ((lane >> 4) << 3);
      hreg[it] = ldg16_cc(src);
    }
    waitv0();  // hstage loads + zx prefetch complete
    const float zx_f = h2f((u16)xf16), zx_i = h2f((u16)xi16);
    const float zx_g = h2f((u16)xg16), zx_o = h2f((u16)xo16);
#pragma unroll
    for (int it = 0; it < 8; ++it) {
      const int kk = (it << 2) + wid;
      Ab[(kk << 6) + lane] = hreg[it];
    }
    __syncthreads();

    f32x4 a0 = fz, a1 = fz, a2 = fz, a3 = fz;
#pragma unroll
    for (int kk = 0; kk < 8; ++kk) {
      const f16x8 av = __builtin_bit_cast(f16x8, Ab[((wid << 3) + kk) * 64 + lane]);
      a0 = mfma_f16(av, wreg[0][kk], a0);
      a1 = mfma_f16(av, wreg[1][kk], a1);
      a2 = mfma_f16(av, wreg[2][kk], a2);
      a3 = mfma_f16(av, wreg[3][kk], a3);
    }
    {
      const int rr = (lane >> 4) << 2;
      const int cc = lane & 15;
#pragma unroll
      for (int r = 0; r < 4; ++r) {
        zb[wid][0][rr + r][cc] = a0[r];
        zb[wid][1][rr + r][cc] = a1[r];
        zb[wid][2][rr + r][cc] = a2[r];
        zb[wid][3][rr + r][cc] = a3[r];
      }
    }
    __syncthreads();

    float zf = zx_f, zi = zx_i, zg = zx_g, zo = zx_o;
#pragma unroll
    for (int w = 0; w < 4; ++w) {
      zf += zb[w][0][b_loc][j_loc];
      zi += zb[w][1][b_loc][j_loc];
      zg += zb[w][2][b_loc][j_loc];
      zo += zb[w][3][b_loc][j_loc];
    }
    const float fgate = sigm(zf);
    const float igate = sigm(zi);
    const float ggate = tanh_(zg);
    const float ogate = sigm(zo);
    creg = creg * fgate + igate * ggate;
    const float hv = ogate * tanh_(creg);

    // critical path first: coherent h store -> drain -> block-wide -> flag
    stg_u16_cc(hstage + ((((size_t)(t + 1)) & 1) << 16) + (b << 10) + jf, (u32)f2h(hv));
    waitv0();
    __syncthreads();
    if (tid == 0) stg_u32_cc(myflag, (u32)(t + 2));

    // off-path: plain cached c/h output stores (drained by kernel-end flush)
    const size_t rowoff = ((size_t)(t * 64 + b)) << 12;
    *(float*)(cb_ + rowoff + ((size_t)jf << 2)) = creg;
    *(float*)(hb_ + rowoff + ((size_t)jf << 2)) = hv;

    // prefetch next step's zx under the barrier wait
    {
      const int tn = (t + 1 < LT) ? t + 1 : t;
      const size_t rown = ((size_t)(tn * 64 + b)) << 12;
      const char* crow = cb_ + rown + (cgp << 6);
      const char* hrow = hb_ + rown + (cgp << 6);
      xf16 = ldg_u16_plain(crow + (j_loc << 1));
      xi16 = ldg_u16_plain(crow + 32 + (j_loc << 1));
      xg16 = ldg_u16_plain(hrow + (j_loc << 1));
      xo16 = ldg_u16_plain(hrow + 32 + (j_loc << 1));
    }
    if (tid < 64) {
      while ((int)ldg_u32_cc(pollflag) < t + 2) {}
    }
    __syncthreads();
  }
}

extern "C" void kernel_launch(void* const* d_in, const int* in_sizes, int n_in, void* d_out,
                              int out_size, void* d_ws, size_t ws_size, hipStream_t stream) {
  const float* x = (const float*)d_in[0];
  const float* c0 = (const float*)d_in[1];
  const float* h0 = (const float*)d_in[2];
  const float* Wf = (const float*)d_in[3];
  const float* bf = (const float*)d_in[4];
  const float* Wi = (const float*)d_in[5];
  const float* bi = (const float*)d_in[6];
  const float* Wg = (const float*)d_in[7];
  const float* bg = (const float*)d_in[8];
  const float* Wo = (const float*)d_in[9];
  const float* bo = (const float*)d_in[10];

  char* ws = (char*)d_ws;
  u32x4* wxp = (u32x4*)(ws + WXP_OFF);
  u32x4* whp = (u32x4*)(ws + WHP_OFF);
  float* bp = (float*)(ws + BIAS_OFF);
  u16* hstage = (u16*)(ws + HSTG_OFF);
  int* flags = (int*)(ws + FLAG_OFF);

  pack_wx<<<1024, 256, 0, stream>>>(Wf, Wi, Wg, Wo, wxp);
  pack_wh<<<2048, 256, 0, stream>>>(Wf, Wi, Wg, Wo, whp);
  pack_bias_flags<<<16, 256, 0, stream>>>(bf, bi, bg, bo, bp, flags);
  zx_gemm<<<8192, 256, 0, stream>>>(x, wxp, bp, (char*)d_out);
  lstm_rec<<<256, 256, 0, stream>>>(c0, h0, whp, (char*)d_out, hstage, flags);
}